// Round 4
// baseline (48.469 us; speedup 1.0000x reference)
//
#include <hip/hip_runtime.h>

// out[b, i*4+p, j*4+q] = sum_k w[p*4+q][k] * patch(b,i,j)[k],  k = kh*16+kw
// MFMA 16x16x32 bf16, A = weights [16o x 32k], B = patches [32k x 16j] -> D[o][j].
// Block: 512 thr / 8 waves; wave = 1 patch-row; 2 j-tiles of 16 patches.
// LDS strip: 72 rows x 264 cols bf16, granule-major, stride 33 granules (no pad).

typedef __attribute__((ext_vector_type(8))) short short8;
typedef __attribute__((ext_vector_type(4))) float f32x4;

#define ROWS 72
#define ROWG 33                 // 16B granules per row (264 bf16), odd -> bank rotation
#define NG   (ROWS * ROWG)      // 2376 granules = 38016 B

__device__ __forceinline__ unsigned pk2(float a, float b) {
    unsigned r;
    asm("v_cvt_pk_bf16_f32 %0, %1, %2" : "=v"(r) : "v"(a), "v"(b));
    return r;   // lo16 = bf16(a), hi16 = bf16(b)
}

__global__ __launch_bounds__(512, 4)
void conv_mfma3(const float* __restrict__ x,
                const float* __restrict__ w,
                float* __restrict__ out) {
    __shared__ uint4 lds[NG];

    const int tid  = threadIdx.x;
    const int lane = tid & 63;
    const int wv   = tid >> 6;          // wave -> patch row i0+wv
    const int bx   = blockIdx.x;        // 0..63
    const int st   = bx & 3;            // column strip (32 patches)
    const int i0   = (bx >> 2) * 8;     // patch-row base (16 i-tiles)
    const int b    = blockIdx.y;

    const float* xb = x + (size_t)b * (1024 * 1024);
    const int basecol = st * 256;
    const int jb      = st * 32;

    // ---- weight fragments (A operand): lane holds w[o=lane&15][s*32+(lane>>4)*8+r]
    const int o = lane & 15;
    short8 wfrag[8];
    #pragma unroll
    for (int s = 0; s < 8; ++s) {
        const float* wp = w + o * 256 + s * 32 + (lane >> 4) * 8;
        float4 w0 = *(const float4*)wp;
        float4 w1 = *(const float4*)(wp + 4);
        uint4 f = make_uint4(pk2(w0.x, w0.y), pk2(w0.z, w0.w),
                             pk2(w1.x, w1.y), pk2(w1.z, w1.w));
        wfrag[s] = __builtin_bit_cast(short8, f);
    }

    // ---- stage x strip -> bf16 LDS (granule-major) ----
    for (int g = tid; g < NG; g += 512) {
        int row = g / ROWG;
        int c8  = g - row * ROWG;                  // 0..32
        int grow = i0 * 8 + row;      if (grow > 1023) grow = 1023;
        int gcol = basecol + c8 * 8;  if (gcol > 1016) gcol = 1016;
        const float* src = xb + grow * 1024 + gcol;
        float4 v0 = *(const float4*)src;
        float4 v1 = *(const float4*)(src + 4);
        lds[g] = make_uint4(pk2(v0.x, v0.y), pk2(v0.z, v0.w),
                            pk2(v1.x, v1.y), pk2(v1.z, v1.w));
    }
    __syncthreads();

    // ---- compute ----
    const int m  = lane & 15;           // patch col within j-tile
    const int kb = (lane >> 4) & 1;     // kw block
    const int hi = lane >> 5;           // kh parity
    const int p  = lane >> 4;           // output sub-row
    const int ip = i0 + wv;
    const int g0 = (wv * 8 + hi) * ROWG + m + kb;   // base granule (s=0, jt=0)

    #pragma unroll
    for (int jt = 0; jt < 2; ++jt) {
        f32x4 acc = {0.f, 0.f, 0.f, 0.f};
        #pragma unroll
        for (int s = 0; s < 8; ++s) {
            short8 a = *(const short8*)&lds[g0 + s * (2 * ROWG) + jt * 16];
            acc = __builtin_amdgcn_mfma_f32_16x16x32_bf16(wfrag[s], a, acc, 0, 0, 0);
        }
        const int jp = jb + jt * 16 + m;
        if (ip < 127 && jp < 127) {
            float* op = out + (size_t)b * (508 * 508) + (ip * 4 + p) * 508 + jp * 4;
            *(float4*)op = *(float4*)&acc;
        }
    }
}

extern "C" void kernel_launch(void* const* d_in, const int* in_sizes, int n_in,
                              void* d_out, int out_size, void* d_ws, size_t ws_size,
                              hipStream_t stream) {
    const float* x = (const float*)d_in[0];
    const float* w = (const float*)d_in[1];
    float* out = (float*)d_out;
    dim3 grid(64, 32);   // (i-tile x col-strip, batch)
    conv_mfma3<<<grid, dim3(512, 1, 1), 0, stream>>>(x, w, out);
}

// Round 5
// 44.408 us; speedup vs baseline: 1.0914x; 1.0914x over previous
//
#include <hip/hip_runtime.h>

// out[b, i*4+p, j*4+q] = sum_k w[p*4+q][k] * patch(b,i,j)[k],  k = kh*16+kw
// MFMA 16x16x32 bf16, A = weights [16o x 32k], B = patches [32k x 16j] -> D[o][patch].
// Block: 256 thr / 4 waves; tile = 16 patch-rows x 16 patch-cols.
// Wave wv owns patch rows i0+wv*4..+3 (4 row-tiles x 8 MFMAs, 4 indep acc chains).
// LDS: bf16 [136 rows][136 cols] as 16B granules, row stride 17 granules (odd -> bank rotation).
// Staging: ALL global loads issued to regs first (1 round-trip), then cvt_pk + ds_write.

typedef __attribute__((ext_vector_type(8))) short short8;
typedef __attribute__((ext_vector_type(4))) float f32x4;

#define NGR   17            // 16B granules per LDS row
#define NROWS 136
#define NG    (NROWS * NGR) // 2312 granules = 36992 B

__device__ __forceinline__ unsigned pk2(float a, float b) {
    unsigned r;
    asm("v_cvt_pk_bf16_f32 %0, %1, %2" : "=v"(r) : "v"(a), "v"(b));
    return r;   // lo16 = bf16(a), hi16 = bf16(b), RNE
}

__device__ __forceinline__ uint4 cvt8(float4 v0, float4 v1) {
    return make_uint4(pk2(v0.x, v0.y), pk2(v0.z, v0.w),
                      pk2(v1.x, v1.y), pk2(v1.z, v1.w));
}

__global__ __launch_bounds__(256, 4)
void conv_mfma4(const float* __restrict__ x,
                const float* __restrict__ w,
                float* __restrict__ out) {
    __shared__ uint4 lds[NG];

    const int tid  = threadIdx.x;
    const int lane = tid & 63;
    const int wv   = tid >> 6;
    const int bx   = blockIdx.x;
    const int jt   = bx & 7;            // j-tile (16 patch cols)
    const int it   = bx >> 3;           // i-tile (16 patch rows)
    const int b    = blockIdx.y;

    const float* xb = x + (size_t)b * (1024 * 1024);
    const int baserow = it * 128;
    const int basecol = jt * 128;

    // ---- phase 1: issue ALL staging loads into registers (one round-trip) ----
    float4 vt0, vt1;
    const bool tail = (tid < 8);
    if (tail) {   // granules 2304..2311 (row 135, c8 9..16)
        int g = 2304 + tid;
        int c8 = g - 135 * NGR;
        int gr = baserow + 135; if (gr > 1023) gr = 1023;
        int gc = basecol + c8 * 8; if (gc > 1016) gc = 1016;
        const float4* s = (const float4*)(xb + gr * 1024 + gc);
        vt0 = s[0]; vt1 = s[1];
    }
    float4 va[18];
    #pragma unroll
    for (int i2 = 0; i2 < 9; ++i2) {
        int g   = tid + i2 * 256;               // <= 2303 < 2312
        int row = g / NGR;
        int c8  = g - row * NGR;
        int gr  = baserow + row;     if (gr > 1023) gr = 1023;
        int gc  = basecol + c8 * 8;  if (gc > 1016) gc = 1016;
        const float4* s = (const float4*)(xb + gr * 1024 + gc);
        va[i2 * 2]     = s[0];
        va[i2 * 2 + 1] = s[1];
    }

    // ---- phase 2: convert + LDS write (addr = linear in g -> base + imm) ----
    #pragma unroll
    for (int i2 = 0; i2 < 9; ++i2) {
        lds[tid + i2 * 256] = cvt8(va[i2 * 2], va[i2 * 2 + 1]);
    }
    if (tail) lds[2304 + tid] = cvt8(vt0, vt1);

    // ---- weight fragments (A operand): lane holds w[o=lane&15][s*32+(lane>>4)*8+r]
    const int o = lane & 15;
    short8 wfrag[8];
    #pragma unroll
    for (int s = 0; s < 8; ++s) {
        const float* wp = w + o * 256 + s * 32 + (lane >> 4) * 8;
        float4 w0 = *(const float4*)wp;
        float4 w1 = *(const float4*)(wp + 4);
        wfrag[s] = __builtin_bit_cast(short8, cvt8(w0, w1));
    }
    __syncthreads();

    // ---- compute: 4 row-tiles per wave, 4 independent MFMA chains ----
    const int m  = lane & 15;           // patch col within tile
    const int kb = (lane >> 4) & 1;     // kw block
    const int hi = lane >> 5;           // kh parity
    const unsigned short* lbase =
        (const unsigned short*)lds + ((wv * 32 + hi) * NGR + m + kb) * 8;
    // element offsets: t (patch row) -> 8 rows = 8*17*8 = 1088; s -> 2 rows = 272

    f32x4 acc[4];
    #pragma unroll
    for (int t = 0; t < 4; ++t) acc[t] = (f32x4){0.f, 0.f, 0.f, 0.f};

    #pragma unroll
    for (int s = 0; s < 8; ++s) {
        short8 a0 = *(const short8*)(lbase + s * 272 + 0 * 1088);
        short8 a1 = *(const short8*)(lbase + s * 272 + 1 * 1088);
        short8 a2 = *(const short8*)(lbase + s * 272 + 2 * 1088);
        short8 a3 = *(const short8*)(lbase + s * 272 + 3 * 1088);
        acc[0] = __builtin_amdgcn_mfma_f32_16x16x32_bf16(wfrag[s], a0, acc[0], 0, 0, 0);
        acc[1] = __builtin_amdgcn_mfma_f32_16x16x32_bf16(wfrag[s], a1, acc[1], 0, 0, 0);
        acc[2] = __builtin_amdgcn_mfma_f32_16x16x32_bf16(wfrag[s], a2, acc[2], 0, 0, 0);
        acc[3] = __builtin_amdgcn_mfma_f32_16x16x32_bf16(wfrag[s], a3, acc[3], 0, 0, 0);
    }

    // ---- epilogue: lane's acc[t][r] = out[ip(t)*4 + p][jp*4 + r], p = lane>>4 ----
    const int p  = lane >> 4;
    const int jp = jt * 16 + m;
    #pragma unroll
    for (int t = 0; t < 4; ++t) {
        const int ip = it * 16 + wv * 4 + t;
        if (ip < 127 && jp < 127) {
            float* op = out + (size_t)b * (508 * 508) + (ip * 4 + p) * 508 + jp * 4;
            *(float4*)op = *(float4*)&acc[t];
        }
    }
}

extern "C" void kernel_launch(void* const* d_in, const int* in_sizes, int n_in,
                              void* d_out, int out_size, void* d_ws, size_t ws_size,
                              hipStream_t stream) {
    const float* x = (const float*)d_in[0];
    const float* w = (const float*)d_in[1];
    float* out = (float*)d_out;
    dim3 grid(64, 32);   // (i-tile*8 + j-tile, batch)
    conv_mfma4<<<grid, dim3(256, 1, 1), 0, stream>>>(x, w, out);
}